// Round 3
// baseline (1342.961 us; speedup 1.0000x reference)
//
#include <hip/hip_runtime.h>
#include <stdint.h>

// Monarch layer: out[b, l*64+j] = bias[l*64+j] + sum_k L[j,k,l] * h1[b,k,j]
//                h1[b,k,j]      = sum_i x[b, k*64+i] * R[k,i,j]
// Fat-wave fused kernel: 512 thr (8 waves, 2/SIMD, <=256 regs), 16 b rows per
// chunk, 4 chunks per WG (grid=256), h1 in LDS, acc in AGPRs, cross-barrier
// x-prefetch in registers, coalesced epilogue via XOR-swizzled LDS restage.
// Precision: bf16x3 split (AhBh + AlBh + AhBl) with fp32 accumulation.

typedef __attribute__((ext_vector_type(8))) short short8;
typedef __attribute__((ext_vector_type(4))) float f32x4;

#define LDS_SB 36                  // words per b-row: 32 k + 4 pad
#define LDS_SJ (16 * LDS_SB + 4)   // 580 words per j-plane
#define LDS_WORDS (64 * LDS_SJ)    // 37120
#define LDS_BYTES (LDS_WORDS * 4)  // 148480 B (1 WG/CU)

__device__ __forceinline__ unsigned short f2bf(float f) {
    unsigned int u = __float_as_uint(f);
    u += 0x7FFFu + ((u >> 16) & 1u);   // RNE
    return (unsigned short)(u >> 16);
}
__device__ __forceinline__ float bf2f(unsigned short h) {
    return __uint_as_float(((unsigned int)h) << 16);
}
__device__ __forceinline__ f32x4 zero4() {
    f32x4 z; z[0] = 0.f; z[1] = 0.f; z[2] = 0.f; z[3] = 0.f; return z;
}
// split two f32x4 (8 contraction elems) into hi/lo bf16 fragments
__device__ __forceinline__ void split2x4(f32x4 a, f32x4 b, short8& hi, short8& lo) {
#pragma unroll
    for (int e = 0; e < 4; ++e) {
        unsigned short h = f2bf(a[e]);
        hi[e] = (short)h; lo[e] = (short)f2bf(a[e] - bf2f(h));
        unsigned short h2 = f2bf(b[e]);
        hi[e + 4] = (short)h2; lo[e + 4] = (short)f2bf(b[e] - bf2f(h2));
    }
}

// ---- prep: coalesced-read fragment builder (unchanged layout from r2) ----
//  R: idx(k,c,jt,lane,e) = (((k*2+c)*4+jt)*64+lane)*8+e
//     value = R[k][c*32 + (lane>>4)*8 + e][jt*16 + (lane&15)]
//  L: idx(j,g,lt,lane,e) = (((j*2+g)*4+lt)*64+lane)*8+e
//     value = L[j][g*32 + (lane>>4)*8 + e][lt*16 + (lane&15)]
__global__ void monarch_prep(const float* __restrict__ L, const float* __restrict__ R,
                             unsigned short* __restrict__ Rt_hi, unsigned short* __restrict__ Rt_lo,
                             unsigned short* __restrict__ Lt_hi, unsigned short* __restrict__ Lt_lo)
{
    int t = blockIdx.x * blockDim.x + threadIdx.x;   // 0 .. 524287
    bool isL = t >= 262144;
    int u = t & 262143;                // linear over source: blk*4096 + row*64 + col
    int blk = u >> 12;
    int row = (u >> 6) & 63;
    int col = u & 63;
    const float* src = isL ? L : R;
    float v = src[u];                  // fully coalesced read
    int c    = row >> 5;
    int hq   = (row >> 3) & 3;
    int e    = row & 7;
    int lane = hq * 16 + (col & 15);
    int tile = col >> 4;
    int idx  = (((blk * 2 + c) * 4 + tile) * 64 + lane) * 8 + e;
    unsigned short h  = f2bf(v);
    unsigned short lo = f2bf(v - bf2f(h));
    if (isL) { Lt_hi[idx] = h; Lt_lo[idx] = lo; }
    else     { Rt_hi[idx] = h; Rt_lo[idx] = lo; }
}

// ---- fused kernel: 512 threads = 8 fat waves, 4 chunks of 16 b rows ----
template<bool USE_WS>
__global__ __launch_bounds__(512, 2) void monarch_fused(
    const float* __restrict__ x,
    const float* __restrict__ L,
    const float* __restrict__ R,
    const float* __restrict__ bias,
    const unsigned short* __restrict__ Rt_hi,
    const unsigned short* __restrict__ Rt_lo,
    const unsigned short* __restrict__ Lt_hi,
    const unsigned short* __restrict__ Lt_lo,
    float* __restrict__ out)
{
    extern __shared__ float h1[];   // stage: [64 j][16 b][LDS_SB]; epilogue: 8x4096 swizzled
    const int tid  = threadIdx.x;
    const int wid  = tid >> 6;      // 0..7
    const int lane = tid & 63;
    const int lr   = lane & 15;
    const int lq   = lane >> 4;     // 0..3
    const int wg   = blockIdx.x;    // 0..255

    // bias columns touched by this thread in the epilogue (hoisted)
    const f32x4 bv0 = *(const f32x4*)(bias + tid * 4);
    const f32x4 bv1 = *(const f32x4*)(bias + tid * 4 + 2048);

    // cross-barrier x prefetch buffer: holds kk=0's 4 f32x4 of the NEXT phase
    f32x4 xpre[4];
    {
        const float* pn = x + ((long)(wg * 16 + lr)) * 4096 + (wid * 4) * 64 + lq * 8;
        xpre[0] = *(const f32x4*)(pn);
        xpre[1] = *(const f32x4*)(pn + 4);
        xpre[2] = *(const f32x4*)(pn + 32);
        xpre[3] = *(const f32x4*)(pn + 36);
    }

    for (int c = 0; c < 4; ++c) {
        const long bchunk = (long)(c * 256 + wg) * 16;
        const float* xr = x + (bchunk + lr) * 4096;

        f32x4 acc[8][4];            // [jj][lt]; j = wid*8+jj  (AGPR-resident)
#pragma unroll
        for (int a = 0; a < 8; ++a)
#pragma unroll
            for (int b = 0; b < 4; ++b) acc[a][b] = zero4();

#pragma unroll
        for (int g = 0; g < 2; ++g) {
            // ---------- stage 1: wave computes k = g*32 + wid*4 + {0..3} ----------
#pragma unroll
            for (int kk = 0; kk < 4; ++kk) {
                const int k  = g * 32 + wid * 4 + kk;
                const int kl = wid * 4 + kk;        // 0..31
                f32x4 x0, x1, x2, x3;
                if (kk == 0) {
                    x0 = xpre[0]; x1 = xpre[1]; x2 = xpre[2]; x3 = xpre[3];
                } else {
                    const float* p = xr + k * 64 + lq * 8;
                    x0 = *(const f32x4*)(p);
                    x1 = *(const f32x4*)(p + 4);
                    x2 = *(const f32x4*)(p + 32);
                    x3 = *(const f32x4*)(p + 36);
                }
                if (kk == 3) {
                    // issue next-phase kk=0 prefetch: flies across barriers/stage2/epilogue
                    const float* pn;
                    if (g == 0) {
                        pn = xr + (32 + wid * 4) * 64 + lq * 8;
                    } else {
                        const int nc = (c + 1) & 3;   // last chunk wraps (data discarded)
                        pn = x + ((long)((nc * 256 + wg) * 16 + lr)) * 4096 + (wid * 4) * 64 + lq * 8;
                    }
                    xpre[0] = *(const f32x4*)(pn);
                    xpre[1] = *(const f32x4*)(pn + 4);
                    xpre[2] = *(const f32x4*)(pn + 32);
                    xpre[3] = *(const f32x4*)(pn + 36);
                }
                short8 ah0, al0, ah1, al1;
                split2x4(x0, x1, ah0, al0);
                split2x4(x2, x3, ah1, al1);
                f32x4 cf[4];
#pragma unroll
                for (int jt = 0; jt < 4; ++jt) cf[jt] = zero4();
#pragma unroll
                for (int c2 = 0; c2 < 2; ++c2) {
                    const short8 ah = c2 ? ah1 : ah0;
                    const short8 al = c2 ? al1 : al0;
#pragma unroll
                    for (int jt = 0; jt < 4; ++jt) {
                        short8 bh, bl;
                        if (USE_WS) {
                            const int idx = (((k * 2 + c2) * 4 + jt) * 64 + lane) * 8;
                            bh = *(const short8*)(Rt_hi + idx);
                            bl = *(const short8*)(Rt_lo + idx);
                        } else {
                            float rv0[4], rv1[4];
#pragma unroll
                            for (int e = 0; e < 4; ++e) {
                                rv0[e] = R[k * 4096 + (c2 * 32 + lq * 8 + e) * 64 + jt * 16 + lr];
                                rv1[e] = R[k * 4096 + (c2 * 32 + lq * 8 + 4 + e) * 64 + jt * 16 + lr];
                            }
                            f32x4 r0 = *(const f32x4*)rv0, r1 = *(const f32x4*)rv1;
                            split2x4(r0, r1, bh, bl);
                        }
                        cf[jt] = __builtin_amdgcn_mfma_f32_16x16x32_bf16(ah, bh, cf[jt], 0, 0, 0);
                        cf[jt] = __builtin_amdgcn_mfma_f32_16x16x32_bf16(al, bh, cf[jt], 0, 0, 0);
                        cf[jt] = __builtin_amdgcn_mfma_f32_16x16x32_bf16(ah, bl, cf[jt], 0, 0, 0);
                    }
                }
                // h1 write: C layout col=lane&15 (j sub), row=(lane>>4)*4+r (b)
#pragma unroll
                for (int jt = 0; jt < 4; ++jt) {
                    const int j = jt * 16 + lr;
#pragma unroll
                    for (int r = 0; r < 4; ++r) {
                        const int b = lq * 4 + r;
                        h1[j * LDS_SJ + b * LDS_SB + kl] = cf[jt][r];
                    }
                }
            }
            __syncthreads();
            // ---------- stage 2: wave handles j = wid*8 + {0..7} ----------
#pragma unroll
            for (int jj = 0; jj < 8; ++jj) {
                const int j = wid * 8 + jj;
                const float* hp = &h1[j * LDS_SJ + lr * LDS_SB + lq * 8];
                f32x4 h0 = *(const f32x4*)(hp);
                f32x4 h4 = *(const f32x4*)(hp + 4);
                short8 ah, al;
                split2x4(h0, h4, ah, al);
#pragma unroll
                for (int lt = 0; lt < 4; ++lt) {
                    short8 bh, bl;
                    if (USE_WS) {
                        const int idx = (((j * 2 + g) * 4 + lt) * 64 + lane) * 8;
                        bh = *(const short8*)(Lt_hi + idx);
                        bl = *(const short8*)(Lt_lo + idx);
                    } else {
                        float lv0[4], lv1[4];
#pragma unroll
                        for (int e = 0; e < 4; ++e) {
                            lv0[e] = L[j * 4096 + (g * 32 + lq * 8 + e) * 64 + lt * 16 + lr];
                            lv1[e] = L[j * 4096 + (g * 32 + lq * 8 + 4 + e) * 64 + lt * 16 + lr];
                        }
                        f32x4 l0 = *(const f32x4*)lv0, l1 = *(const f32x4*)lv1;
                        split2x4(l0, l1, bh, bl);
                    }
                    acc[jj][lt] = __builtin_amdgcn_mfma_f32_16x16x32_bf16(ah, bh, acc[jj][lt], 0, 0, 0);
                    acc[jj][lt] = __builtin_amdgcn_mfma_f32_16x16x32_bf16(al, bh, acc[jj][lt], 0, 0, 0);
                    acc[jj][lt] = __builtin_amdgcn_mfma_f32_16x16x32_bf16(ah, bl, acc[jj][lt], 0, 0, 0);
                }
            }
            __syncthreads();
        }

        // ---------- epilogue: acc -> swizzled LDS (b128) -> coalesced stores ----------
        // logical word w = b7*4096 + l*64 + j ; unit = w>>2 ; phys = unit ^ ((unit>>4)&15)
#pragma unroll
        for (int p2 = 0; p2 < 2; ++p2) {
            if ((lq >> 1) == p2) {
#pragma unroll
                for (int lt = 0; lt < 4; ++lt) {
                    const int l = lt * 16 + lr;
#pragma unroll
                    for (int r = 0; r < 4; ++r) {
                        const int b7 = (lq & 1) * 4 + r;
#pragma unroll
                        for (int q = 0; q < 2; ++q) {
                            const int w = b7 * 4096 + l * 64 + wid * 8 + q * 4;
                            const int unit = w >> 2;
                            const int phys = unit ^ ((unit >> 4) & 15);
                            f32x4 v;
                            v[0] = acc[q * 4 + 0][lt][r];
                            v[1] = acc[q * 4 + 1][lt][r];
                            v[2] = acc[q * 4 + 2][lt][r];
                            v[3] = acc[q * 4 + 3][lt][r];
                            *(f32x4*)(&h1[phys * 4]) = v;
                        }
                    }
                }
            }
            __syncthreads();
#pragma unroll
            for (int row = 0; row < 8; ++row) {
#pragma unroll
                for (int hf = 0; hf < 2; ++hf) {
                    const int u = row * 1024 + hf * 512 + tid;
                    const int phys = u ^ ((u >> 4) & 15);
                    f32x4 v = *(const f32x4*)(&h1[phys * 4]);
                    const f32x4 bv = hf ? bv1 : bv0;
                    v[0] += bv[0]; v[1] += bv[1]; v[2] += bv[2]; v[3] += bv[3];
                    *(f32x4*)(&out[(bchunk + p2 * 8 + row) * 4096 + hf * 2048 + tid * 4]) = v;
                }
            }
            __syncthreads();   // p2==1 instance also protects h1 reuse by next chunk
        }
    }
}

extern "C" void kernel_launch(void* const* d_in, const int* in_sizes, int n_in,
                              void* d_out, int out_size, void* d_ws, size_t ws_size,
                              hipStream_t stream)
{
    const float* x    = (const float*)d_in[0];
    const float* L    = (const float*)d_in[1];
    const float* R    = (const float*)d_in[2];
    const float* bias = (const float*)d_in[3];
    float* out = (float*)d_out;

    const size_t WS_NEED = 4ull * 262144ull * sizeof(unsigned short);  // 2 MiB
    const bool use_ws = (d_ws != nullptr) && (ws_size >= WS_NEED);

    if (use_ws) {
        unsigned short* rt_hi = (unsigned short*)d_ws;
        unsigned short* rt_lo = rt_hi + 262144;
        unsigned short* lt_hi = rt_lo + 262144;
        unsigned short* lt_lo = lt_hi + 262144;
        monarch_prep<<<2048, 256, 0, stream>>>(L, R, rt_hi, rt_lo, lt_hi, lt_lo);
        (void)hipFuncSetAttribute(reinterpret_cast<const void*>(&monarch_fused<true>),
                                  hipFuncAttributeMaxDynamicSharedMemorySize, LDS_BYTES);
        monarch_fused<true><<<256, 512, LDS_BYTES, stream>>>(
            x, L, R, bias, rt_hi, rt_lo, lt_hi, lt_lo, out);
    } else {
        (void)hipFuncSetAttribute(reinterpret_cast<const void*>(&monarch_fused<false>),
                                  hipFuncAttributeMaxDynamicSharedMemorySize, LDS_BYTES);
        monarch_fused<false><<<256, 512, LDS_BYTES, stream>>>(
            x, L, R, bias, nullptr, nullptr, nullptr, nullptr, out);
    }
}

// Round 5
// 613.169 us; speedup vs baseline: 2.1902x; 2.1902x over previous
//
#include <hip/hip_runtime.h>
#include <stdint.h>

// Monarch layer: out[b, l*64+j] = bias[l*64+j] + sum_k L[j,k,l] * h1[b,k,j]
//                h1[b,k,j]      = sum_i x[b, k*64+i] * R[k,i,j]
// Pipelined fused kernel: 1024 thr (16 waves), 16 b-rows per WG, h1 split into
// 4 k-units of 16 with two LDS buffers; stage1(produce, HBM+MFMA) overlaps
// stage2(consume, LDS+L2+MFMA) each phase. bf16x3 split, fp32 accum.
// LDS layout per unit: [64 j][16 k][16 b] with b-group rotation s=(b>>2+k>>2)&3
// and SJ=260 -> conflict-free b128 stage1 writes, 2-way stage2 reads.

typedef __attribute__((ext_vector_type(8))) short short8;
typedef __attribute__((ext_vector_type(4))) float f32x4;

#define SJ_U 260                    // words per j-plane within a unit (16k*16b + 4 pad)
#define UBUF (64 * SJ_U)            // 16640 words per unit buffer
#define LDS_WORDS (2 * UBUF)        // 33280 words
#define LDS_BYTES (LDS_WORDS * 4)   // 133120 B  (restage needs 32768 words <= 33280)

__device__ __forceinline__ unsigned short f2bf(float f) {
    unsigned int u = __float_as_uint(f);
    u += 0x7FFFu + ((u >> 16) & 1u);   // RNE
    return (unsigned short)(u >> 16);
}
__device__ __forceinline__ float bf2f(unsigned short h) {
    return __uint_as_float(((unsigned int)h) << 16);
}
__device__ __forceinline__ f32x4 zero4() {
    f32x4 z; z[0] = 0.f; z[1] = 0.f; z[2] = 0.f; z[3] = 0.f; return z;
}
// split two f32x4 (8 contraction elems) into hi/lo bf16 fragments
__device__ __forceinline__ void split2x4(f32x4 a, f32x4 b, short8& hi, short8& lo) {
#pragma unroll
    for (int e = 0; e < 4; ++e) {
        unsigned short h = f2bf(a[e]);
        hi[e] = (short)h; lo[e] = (short)f2bf(a[e] - bf2f(h));
        unsigned short h2 = f2bf(b[e]);
        hi[e + 4] = (short)h2; lo[e + 4] = (short)f2bf(b[e] - bf2f(h2));
    }
}

// ---- prep: coalesced-read fragment builder (layout unchanged since r2) ----
//  R: idx(k,c,jt,lane,e) = (((k*2+c)*4+jt)*64+lane)*8+e
//     value = R[k][c*32 + (lane>>4)*8 + e][jt*16 + (lane&15)]
//  L: idx(j,g,lt,lane,e) = (((j*2+g)*4+lt)*64+lane)*8+e
//     value = L[j][g*32 + (lane>>4)*8 + e][lt*16 + (lane&15)]
__global__ void monarch_prep(const float* __restrict__ L, const float* __restrict__ R,
                             unsigned short* __restrict__ Rt_hi, unsigned short* __restrict__ Rt_lo,
                             unsigned short* __restrict__ Lt_hi, unsigned short* __restrict__ Lt_lo)
{
    int t = blockIdx.x * blockDim.x + threadIdx.x;   // 0 .. 524287
    bool isL = t >= 262144;
    int u = t & 262143;                // linear over source: blk*4096 + row*64 + col
    int blk = u >> 12;
    int row = (u >> 6) & 63;
    int col = u & 63;
    const float* src = isL ? L : R;
    float v = src[u];                  // fully coalesced read
    int c    = row >> 5;
    int hq   = (row >> 3) & 3;
    int e    = row & 7;
    int lane = hq * 16 + (col & 15);
    int tile = col >> 4;
    int idx  = (((blk * 2 + c) * 4 + tile) * 64 + lane) * 8 + e;
    unsigned short h  = f2bf(v);
    unsigned short lo = f2bf(v - bf2f(h));
    if (isL) { Lt_hi[idx] = h; Lt_lo[idx] = lo; }
    else     { Rt_hi[idx] = h; Rt_lo[idx] = lo; }
}

// ---- fused kernel: 1024 threads = 16 waves, 4-unit software pipeline ----
template<bool USE_WS>
__global__ __launch_bounds__(1024, 3) void monarch_fused(
    const float* __restrict__ x,
    const float* __restrict__ L,
    const float* __restrict__ R,
    const float* __restrict__ bias,
    const unsigned short* __restrict__ Rt_hi,
    const unsigned short* __restrict__ Rt_lo,
    const unsigned short* __restrict__ Lt_hi,
    const unsigned short* __restrict__ Lt_lo,
    float* __restrict__ out)
{
    extern __shared__ float h1[];   // 2 unit buffers; epilogue: 8x4096 swizzled restage
    const int tid  = threadIdx.x;
    const int wid  = tid >> 6;      // 0..15
    const int lane = tid & 63;
    const int lr   = lane & 15;
    const int lq   = lane >> 4;     // 0..3
    const int lq1  = lq & 1;
    const long b0  = (long)blockIdx.x * 16;

    f32x4 acc[4][4];                // [jj][lt]; j = wid*4+jj
#pragma unroll
    for (int a = 0; a < 4; ++a)
#pragma unroll
        for (int b = 0; b < 4; ++b) acc[a][b] = zero4();

    const float* xrow = x + (b0 + lr) * 4096;
    const int jbase = wid * 4;

    f32x4 xr[4];   // in-flight x for the unit being produced (k = u*16 + wid)

    // ---- X_ISSUE(u): load x[b=lr][k_glob*64 + lq*8 + {0..3,4..7,32..35,36..39}]
#define X_ISSUE(U)                                                        \
    {                                                                     \
        const float* p = xrow + (((U) * 16 + wid) << 6) + lq * 8;         \
        xr[0] = *(const f32x4*)(p);                                       \
        xr[1] = *(const f32x4*)(p + 4);                                   \
        xr[2] = *(const f32x4*)(p + 32);                                  \
        xr[3] = *(const f32x4*)(p + 36);                                  \
    }

    // ---- S1_COMPUTE(u): consume xr, produce unit u into buf (u&1)
#define S1_COMPUTE(U)                                                     \
    {                                                                     \
        const int kg   = (U) * 16 + wid;                                  \
        const int boff = ((U) & 1) * UBUF;                                \
        short8 ah0, al0, ah1, al1;                                        \
        split2x4(xr[0], xr[1], ah0, al0);                                 \
        split2x4(xr[2], xr[3], ah1, al1);                                 \
        f32x4 cf[4];                                                      \
        _Pragma("unroll")                                                 \
        for (int jt = 0; jt < 4; ++jt) cf[jt] = zero4();                  \
        _Pragma("unroll")                                                 \
        for (int c2 = 0; c2 < 2; ++c2) {                                  \
            const short8 ah = c2 ? ah1 : ah0;                             \
            const short8 al = c2 ? al1 : al0;                             \
            _Pragma("unroll")                                             \
            for (int jt = 0; jt < 4; ++jt) {                              \
                short8 bh, bl;                                            \
                if (USE_WS) {                                             \
                    const int idx = (((kg * 2 + c2) * 4 + jt) * 64 + lane) * 8; \
                    bh = *(const short8*)(Rt_hi + idx);                   \
                    bl = *(const short8*)(Rt_lo + idx);                   \
                } else {                                                  \
                    float rv0[4], rv1[4];                                 \
                    _Pragma("unroll")                                     \
                    for (int e = 0; e < 4; ++e) {                         \
                        rv0[e] = R[kg * 4096 + (c2 * 32 + lq * 8 + e) * 64 + jt * 16 + lr]; \
                        rv1[e] = R[kg * 4096 + (c2 * 32 + lq * 8 + 4 + e) * 64 + jt * 16 + lr]; \
                    }                                                     \
                    f32x4 r0 = *(const f32x4*)rv0, r1 = *(const f32x4*)rv1; \
                    split2x4(r0, r1, bh, bl);                             \
                }                                                         \
                cf[jt] = __builtin_amdgcn_mfma_f32_16x16x32_bf16(ah, bh, cf[jt], 0, 0, 0); \
                cf[jt] = __builtin_amdgcn_mfma_f32_16x16x32_bf16(al, bh, cf[jt], 0, 0, 0); \
                cf[jt] = __builtin_amdgcn_mfma_f32_16x16x32_bf16(ah, bl, cf[jt], 0, 0, 0); \
            }                                                             \
        }                                                                 \
        const int s = (lq + (wid >> 2)) & 3;                              \
        _Pragma("unroll")                                                 \
        for (int jt = 0; jt < 4; ++jt) {                                  \
            const int j = jt * 16 + lr;                                   \
            *(f32x4*)(&h1[boff + j * SJ_U + wid * 16 + 4 * s]) = cf[jt];  \
        }                                                                 \
    }

    // ---- S2(u): consume unit u from buf (u&1) into acc (K=32 MFMA, upper half zeroed)
#define S2_CONSUME(U)                                                     \
    {                                                                     \
        const int boff = ((U) & 1) * UBUF;                                \
        const int s_lo = ((lr >> 2) + 2 * lq1) & 3;                       \
        const int s_hi = (s_lo + 1) & 3;                                  \
        _Pragma("unroll")                                                 \
        for (int jj = 0; jj < 4; ++jj) {                                  \
            const int j = jbase + jj;                                     \
            const float* hb = &h1[boff + j * SJ_U + lq1 * 128 + (lr & 3)]; \
            float ha[8];                                                  \
            _Pragma("unroll")                                             \
            for (int e = 0; e < 4; ++e) {                                 \
                ha[e]     = (lq < 2) ? hb[e * 16 + 4 * s_lo]      : 0.0f; \
                ha[4 + e] = (lq < 2) ? hb[64 + e * 16 + 4 * s_hi] : 0.0f; \
            }                                                             \
            f32x4 h0, h4;                                                 \
            _Pragma("unroll")                                             \
            for (int e = 0; e < 4; ++e) { h0[e] = ha[e]; h4[e] = ha[4 + e]; } \
            short8 ah, al;                                                \
            split2x4(h0, h4, ah, al);                                     \
            const int lane2 = (2 * ((U) & 1) + lq1) * 16 + lr;            \
            _Pragma("unroll")                                             \
            for (int lt = 0; lt < 4; ++lt) {                              \
                short8 bh, bl;                                            \
                if (USE_WS) {                                             \
                    const int idx = (((j * 2 + ((U) >> 1)) * 4 + lt) * 64 + lane2) * 8; \
                    bh = *(const short8*)(Lt_hi + idx);                   \
                    bl = *(const short8*)(Lt_lo + idx);                   \
                } else {                                                  \
                    float lv0[4], lv1[4];                                 \
                    _Pragma("unroll")                                     \
                    for (int e = 0; e < 4; ++e) {                         \
                        lv0[e] = L[j * 4096 + ((U) * 16 + lq1 * 8 + e) * 64 + lt * 16 + lr]; \
                        lv1[e] = L[j * 4096 + ((U) * 16 + lq1 * 8 + 4 + e) * 64 + lt * 16 + lr]; \
                    }                                                     \
                    f32x4 l0 = *(const f32x4*)lv0, l1 = *(const f32x4*)lv1; \
                    split2x4(l0, l1, bh, bl);                             \
                }                                                         \
                acc[jj][lt] = __builtin_amdgcn_mfma_f32_16x16x32_bf16(ah, bh, acc[jj][lt], 0, 0, 0); \
                acc[jj][lt] = __builtin_amdgcn_mfma_f32_16x16x32_bf16(al, bh, acc[jj][lt], 0, 0, 0); \
                acc[jj][lt] = __builtin_amdgcn_mfma_f32_16x16x32_bf16(ah, bl, acc[jj][lt], 0, 0, 0); \
            }                                                             \
        }                                                                 \
    }

    // ---- pipeline: S1(0); { S2(u) || S1(u+1) } for u=0..2; S2(3) ----
    X_ISSUE(0)
    S1_COMPUTE(0)
    __syncthreads();

#pragma unroll
    for (int u = 0; u < 4; ++u) {
        if (u < 3) { X_ISSUE(u + 1) }      // HBM loads fly over S2's work
        switch (u) {                        // keep (U) literal for const-folding
            case 0: S2_CONSUME(0) break;
            case 1: S2_CONSUME(1) break;
            case 2: S2_CONSUME(2) break;
            default: S2_CONSUME(3) break;
        }
        if (u < 3) {
            switch (u) {
                case 0: S1_COMPUTE(1) break;
                case 1: S1_COMPUTE(2) break;
                default: S1_COMPUTE(3) break;
            }
        }
        __syncthreads();
    }

    // ---- epilogue: acc -> swizzled LDS (b128) -> coalesced dwordx4 stores ----
    // logical word w = b7*4096 + l*64 + j ; unit = w>>2 ; phys = unit ^ ((unit>>4)&15)
    const f32x4 bv = *(const f32x4*)(bias + tid * 4);
#pragma unroll
    for (int p = 0; p < 2; ++p) {
        if ((lq >> 1) == p) {
#pragma unroll
            for (int lt = 0; lt < 4; ++lt) {
                const int l = lt * 16 + lr;
#pragma unroll
                for (int r = 0; r < 4; ++r) {
                    const int b7 = lq1 * 4 + r;
                    const int w = b7 * 4096 + l * 64 + jbase;
                    const int unit = w >> 2;
                    const int phys = unit ^ ((unit >> 4) & 15);
                    f32x4 v;
                    v[0] = acc[0][lt][r]; v[1] = acc[1][lt][r];
                    v[2] = acc[2][lt][r]; v[3] = acc[3][lt][r];
                    *(f32x4*)(&h1[phys * 4]) = v;
                }
            }
        }
        __syncthreads();
#pragma unroll
        for (int it = 0; it < 8; ++it) {
            const int ui = it * 1024 + tid;
            const int phys = ui ^ ((ui >> 4) & 15);
            f32x4 v = *(const f32x4*)(&h1[phys * 4]);
            v[0] += bv[0]; v[1] += bv[1]; v[2] += bv[2]; v[3] += bv[3];
            *(f32x4*)(&out[(b0 + p * 8 + it) * 4096 + tid * 4]) = v;
        }
        if (p == 0) __syncthreads();
    }
#undef X_ISSUE
#undef S1_COMPUTE
#undef S2_CONSUME
}

extern "C" void kernel_launch(void* const* d_in, const int* in_sizes, int n_in,
                              void* d_out, int out_size, void* d_ws, size_t ws_size,
                              hipStream_t stream)
{
    const float* x    = (const float*)d_in[0];
    const float* L    = (const float*)d_in[1];
    const float* R    = (const float*)d_in[2];
    const float* bias = (const float*)d_in[3];
    float* out = (float*)d_out;

    const size_t WS_NEED = 4ull * 262144ull * sizeof(unsigned short);  // 2 MiB
    const bool use_ws = (d_ws != nullptr) && (ws_size >= WS_NEED);

    if (use_ws) {
        unsigned short* rt_hi = (unsigned short*)d_ws;
        unsigned short* rt_lo = rt_hi + 262144;
        unsigned short* lt_hi = rt_lo + 262144;
        unsigned short* lt_lo = lt_hi + 262144;
        monarch_prep<<<2048, 256, 0, stream>>>(L, R, rt_hi, rt_lo, lt_hi, lt_lo);
        (void)hipFuncSetAttribute(reinterpret_cast<const void*>(&monarch_fused<true>),
                                  hipFuncAttributeMaxDynamicSharedMemorySize, LDS_BYTES);
        monarch_fused<true><<<1024, 1024, LDS_BYTES, stream>>>(
            x, L, R, bias, rt_hi, rt_lo, lt_hi, lt_lo, out);
    } else {
        (void)hipFuncSetAttribute(reinterpret_cast<const void*>(&monarch_fused<false>),
                                  hipFuncAttributeMaxDynamicSharedMemorySize, LDS_BYTES);
        monarch_fused<false><<<1024, 1024, LDS_BYTES, stream>>>(
            x, L, R, bias, nullptr, nullptr, nullptr, nullptr, out);
    }
}